// Round 5
// baseline (312.271 us; speedup 1.0000x reference)
//
#include <hip/hip_runtime.h>

#define N_ROWS 65536
#define DIM 64
#define KCB 1024
#define Q_ELEMS 4194304   // 64*64*32*32
#define RPB 128           // rows per block
#define KQ 256            // codewords per wave (K-quarter)

// ws layout (bytes): [0,4096) float wn2[1024]; [4096,6144) float partial[512]

// Bit-exact replica of numpy's pairwise sum of squares for 64 fp32 values.
__device__ __forceinline__ float np_pairwise_sumsq64(const float* v) {
#pragma clang fp contract(off)
    float r[8];
#pragma unroll
    for (int j = 0; j < 8; ++j) r[j] = v[j] * v[j];
#pragma unroll
    for (int i = 8; i < 64; i += 8) {
#pragma unroll
        for (int j = 0; j < 8; ++j) {
            float s = v[i + j] * v[i + j];
            r[j] = r[j] + s;
        }
    }
    return ((r[0] + r[1]) + (r[2] + r[3])) + ((r[4] + r[5]) + (r[6] + r[7]));
}

__global__ void wnorm_kernel(const float* __restrict__ w, float* __restrict__ wn2) {
    int k = blockIdx.x * 256 + threadIdx.x;
    if (k >= KCB) return;
    wn2[k] = np_pairwise_sumsq64(w + (size_t)k * DIM);
}

__global__ __launch_bounds__(256, 3) void vq_kernel(const float* __restrict__ x,
                                                    const float* __restrict__ w,
                                                    const float* __restrict__ wn2,
                                                    float* __restrict__ out,
                                                    float* __restrict__ partial) {
    const int t = threadIdx.x;
    const int lane = t & 63;
    // readfirstlane: make the wave id (and thus all weight addresses) SGPR-
    // resident so the backend promotes weight loads to SMEM (s_load), keeping
    // the VALU issue slots for FMAs only.
    const int wv = __builtin_amdgcn_readfirstlane(t >> 6);
    const int rowbase = blockIdx.x * RPB;
    const int r0 = rowbase + lane;           // this thread's two rows
    const int r1 = r0 + 64;

    // x rows -> 128 VGPRs
    float xr0[DIM], xr1[DIM];
    const float4* xv0 = (const float4*)(x + (size_t)r0 * DIM);
    const float4* xv1 = (const float4*)(x + (size_t)r1 * DIM);
#pragma unroll
    for (int i = 0; i < 16; ++i) {
        float4 a = xv0[i];
        xr0[4 * i + 0] = a.x; xr0[4 * i + 1] = a.y; xr0[4 * i + 2] = a.z; xr0[4 * i + 3] = a.w;
        float4 b = xv1[i];
        xr1[4 * i + 0] = b.x; xr1[4 * i + 1] = b.y; xr1[4 * i + 2] = b.z; xr1[4 * i + 3] = b.w;
    }
    const float S0 = np_pairwise_sumsq64(xr0);
    const float S1 = np_pairwise_sumsq64(xr1);

    const int kbase = wv * KQ;               // this wave's K-quarter
    const float* __restrict__ wq = w + (size_t)kbase * DIM;
    float best0 = 3.4e38f, best1 = 3.4e38f;
    int bi0 = kbase, bi1 = kbase;

    // One codeword per iteration: 64 SGPRs of weights (s_load_dwordx16 x4),
    // 128 FMAs (two independent chains -> full issue rate). unroll 1 pins the
    // SGPR working set to one codeword (2 would exceed the ~102-SGPR budget
    // and spill to VGPR lanes).
#pragma unroll 1
    for (int c = 0; c < KQ; ++c) {
        const float* wr = wq + c * DIM;      // wave-uniform -> SMEM
        float a0 = 0.f, a1 = 0.f;
#pragma unroll
        for (int d = 0; d < DIM; ++d) {
            float wd = wr[d];
            a0 = __builtin_fmaf(xr0[d], wd, a0);
            a1 = __builtin_fmaf(xr1[d], wd, a1);
        }
        const int k = kbase + c;
        const float wnk = wn2[k];            // uniform -> s_load
        // 2*a exact; (A - 2a) one rounding contracted or not -> bit-exact
        float d0 = (S0 + wnk) - 2.0f * a0;
        float d1 = (S1 + wnk) - 2.0f * a1;
        if (d0 < best0) { best0 = d0; bi0 = k; }
        if (d1 < best1) { best1 = d1; bi1 = k; }
    }

    // cross-quarter argmin combine (ascending q + strict < == numpy
    // first-occurrence argmin over full K; proven bit-exact in R3/R4)
    __shared__ float cbd[4][RPB];
    __shared__ int   cbk[4][RPB];
    __shared__ float red[4];
    cbd[wv][lane]      = best0;  cbk[wv][lane]      = bi0;
    cbd[wv][64 + lane] = best1;  cbk[wv][64 + lane] = bi1;
    __syncthreads();

    float lsum = 0.f;
    if (t < 128) {
        const int rb = t;                    // row-in-block
        float bd = cbd[0][rb]; int bk = cbk[0][rb];
#pragma unroll
        for (int q = 1; q < 4; ++q) {
            float dq = cbd[q][rb]; int kq = cbk[q][rb];
            if (dq < bd) { bd = dq; bk = kq; }
        }
        // thread t holds row rowbase+t in xr0 (wave0) / xr1 (wave1)
        float xcur[DIM];
        if (wv == 0) {
#pragma unroll
            for (int d = 0; d < DIM; ++d) xcur[d] = xr0[d];
        } else {
#pragma unroll
            for (int d = 0; d < DIM; ++d) xcur[d] = xr1[d];
        }
        const int n = rowbase + rb;
        const int b = n >> 10;               // H*W = 1024
        const int hw = n & 1023;
        float* outq = out + 1 + (size_t)b * 65536 + hw;
        const float4* wr4 = (const float4*)(w + (size_t)bk * DIM);
#pragma unroll
        for (int i = 0; i < 16; ++i) {
            float4 u = wr4[i];
            float d0 = u.x - xcur[4 * i + 0];
            float d1 = u.y - xcur[4 * i + 1];
            float d2 = u.z - xcur[4 * i + 2];
            float d3 = u.w - xcur[4 * i + 3];
            lsum += d0 * d0; lsum += d1 * d1; lsum += d2 * d2; lsum += d3 * d3;
            outq[(size_t)(4 * i + 0) * 1024] = xcur[4 * i + 0] + d0;
            outq[(size_t)(4 * i + 1) * 1024] = xcur[4 * i + 1] + d1;
            outq[(size_t)(4 * i + 2) * 1024] = xcur[4 * i + 2] + d2;
            outq[(size_t)(4 * i + 3) * 1024] = xcur[4 * i + 3] + d3;
        }
        out[1 + Q_ELEMS + n] = (float)bk;
    }
#pragma unroll
    for (int off = 32; off > 0; off >>= 1) lsum += __shfl_down(lsum, off, 64);
    if (lane == 0) red[wv] = lsum;
    __syncthreads();
    if (t == 0) partial[blockIdx.x] = (red[0] + red[1]) + (red[2] + red[3]);
}

__global__ void finish_kernel(const float* __restrict__ partial, float* __restrict__ out) {
    float v = partial[threadIdx.x] + partial[threadIdx.x + 256];
#pragma unroll
    for (int off = 32; off > 0; off >>= 1) v += __shfl_down(v, off, 64);
    __shared__ float red[4];
    const int lane = threadIdx.x & 63;
    const int wv = threadIdx.x >> 6;
    if (lane == 0) red[wv] = v;
    __syncthreads();
    if (threadIdx.x == 0) {
        float total = (red[0] + red[1]) + (red[2] + red[3]);
        out[0] = total * (2.0f / (float)(N_ROWS * DIM));
    }
}

extern "C" void kernel_launch(void* const* d_in, const int* in_sizes, int n_in,
                              void* d_out, int out_size, void* d_ws, size_t ws_size,
                              hipStream_t stream) {
    const float* x = (const float*)d_in[0];
    const float* w = (const float*)d_in[1];
    float* out = (float*)d_out;

    char* ws = (char*)d_ws;
    float* wn2 = (float*)(ws + 0);
    float* partial = (float*)(ws + 4096);

    wnorm_kernel<<<4, 256, 0, stream>>>(w, wn2);
    vq_kernel<<<N_ROWS / RPB, 256, 0, stream>>>(x, w, wn2, out, partial);
    finish_kernel<<<1, 256, 0, stream>>>(partial, out);
}